// Round 9
// baseline (308.037 us; speedup 1.0000x reference)
//
#include <hip/hip_runtime.h>
#include <math.h>

#define SELU_LAMBDA 1.0507009873554805f
#define SELU_ALPHA  1.6732632423543772f

#define BSHIFT 9
#define BNODES 512          // nodes per bucket
#define CAP    10240        // bucket capacity (mean 8192, +22 sigma)
#define CHUNK  4096         // edges per k_bin block
#define NSLOT  64           // stats atomic spreading slots

// bf16 helpers (round-to-nearest-even via bias trick; inputs are finite)
__device__ __forceinline__ unsigned short f2bf(float f) {
  unsigned int u = __float_as_uint(f);
  u += 0x7FFF + ((u >> 16) & 1);
  return (unsigned short)(u >> 16);
}
__device__ __forceinline__ float bf2f(unsigned short u) {
  return __uint_as_float(((unsigned int)u) << 16);
}
// accumulate 8 bf16 (one uint4) into a[0..7]
__device__ __forceinline__ void acc8(uint4 v, float* a) {
  unsigned int w0 = v.x, w1 = v.y, w2 = v.z, w3 = v.w;
  a[0] += __uint_as_float(w0 << 16);
  a[1] += __uint_as_float(w0 & 0xFFFF0000u);
  a[2] += __uint_as_float(w1 << 16);
  a[3] += __uint_as_float(w1 & 0xFFFF0000u);
  a[4] += __uint_as_float(w2 << 16);
  a[5] += __uint_as_float(w2 & 0xFFFF0000u);
  a[6] += __uint_as_float(w3 << 16);
  a[7] += __uint_as_float(w3 & 0xFFFF0000u);
}
__device__ __forceinline__ uint4 pack8(const float* a) {
  uint4 o;
  o.x = (unsigned int)f2bf(a[0]) | ((unsigned int)f2bf(a[1]) << 16);
  o.y = (unsigned int)f2bf(a[2]) | ((unsigned int)f2bf(a[3]) << 16);
  o.z = (unsigned int)f2bf(a[4]) | ((unsigned int)f2bf(a[5]) << 16);
  o.w = (unsigned int)f2bf(a[6]) | ((unsigned int)f2bf(a[7]) << 16);
  return o;
}

// ---------------------------------------------------------------- setup: zero cursor/stats
__global__ __launch_bounds__(256) void k_zero(int* __restrict__ cursor,
    float* __restrict__ stats) {
  int i = blockIdx.x * 256 + threadIdx.x;
  if (i < 256) cursor[i] = 0;
  if (i < NSLOT * 128) stats[i] = 0.f;
}

// ---------------------------------------------------------------- phase 1: bin edges by dst bucket
// packed entry: src | (dstLocal << 17)   (src < 2^17, dstLocal < 2^9)
__global__ __launch_bounds__(256) void k_bin(const int* __restrict__ src,
    const int* __restrict__ dst, int* __restrict__ cursor,
    int* __restrict__ binned, int e) {
  __shared__ int hist[256];
  __shared__ int gb[256];
  const int tid = threadIdx.x;
  hist[tid] = 0;
  __syncthreads();
  const int base = blockIdx.x * CHUNK;
  int bk[16], rk[16], pk[16];
#pragma unroll
  for (int k = 0; k < 16; ++k) {
    int i = base + k * 256 + tid;
    if (i < e) {
      int d = dst[i];
      int s = src[i];
      int b = d >> BSHIFT;
      bk[k] = b;
      pk[k] = s | ((d & (BNODES - 1)) << 17);
      rk[k] = atomicAdd(&hist[b], 1);
    } else {
      bk[k] = -1;
    }
  }
  __syncthreads();
  int h = hist[tid];
  if (h > 0) gb[tid] = atomicAdd(&cursor[tid], h);
  __syncthreads();
#pragma unroll
  for (int k = 0; k < 16; ++k) {
    if (bk[k] >= 0) binned[bk[k] * CAP + gb[bk[k]] + rk[k]] = pk[k];
  }
}

// ---------------------------------------------------------------- phase 2: per-bucket CSR build (one wg owns one bucket)
__global__ __launch_bounds__(256) void k_build(const int* __restrict__ binned,
    const int* __restrict__ cursor, int* __restrict__ offs,
    int* __restrict__ csr, int n, int nb, int etot) {
  __shared__ int sc[2][256];
  __shared__ int deg[BNODES];
  __shared__ int pre[BNODES];
  __shared__ int wsum[4];
  __shared__ int stage[CAP];
  __shared__ int s_cbase;
  const int b = blockIdx.x;
  const int tid = threadIdx.x;

  // replicated inclusive scan of the nb bucket counts
  int v0 = (tid < nb) ? cursor[tid] : 0;
  sc[0][tid] = v0;
  __syncthreads();
  int cur = 0;
  for (int d = 1; d < 256; d <<= 1) {
    int t = sc[cur][tid];
    if (tid >= d) t += sc[cur][tid - d];
    sc[cur ^ 1][tid] = t;
    cur ^= 1;
    __syncthreads();
  }
  if (tid == 0) {
    s_cbase = (b == 0) ? 0 : sc[cur][b - 1];
    if (b == 0) offs[n] = etot;
  }
  deg[tid] = 0;
  deg[tid + 256] = 0;
  __syncthreads();
  const int cbase = s_cbase;
  const int cnt = sc[cur][b] - cbase;

  const int nodeBase = b << BSHIFT;
  const int* gsrc = binned + b * CAP;

  for (int i = tid; i < cnt; i += 256) atomicAdd(&deg[gsrc[i] >> 17], 1);
  __syncthreads();

  // exclusive scan of deg[512]: 2 elements/thread
  const int lane = tid & 63, w = tid >> 6;
  int a0 = deg[2 * tid], a1 = deg[2 * tid + 1];
  int ps = a0 + a1;
  int s = ps;
#pragma unroll
  for (int d = 1; d < 64; d <<= 1) {
    int t = __shfl_up(s, d, 64);
    if (lane >= d) s += t;
  }
  if (lane == 63) wsum[w] = s;
  __syncthreads();
  if (tid == 0) {
    int acc = 0;
#pragma unroll
    for (int j = 0; j < 4; ++j) { int t = wsum[j]; wsum[j] = acc; acc += t; }
  }
  __syncthreads();
  int ex = wsum[w] + s - ps;
  pre[2 * tid] = ex;
  pre[2 * tid + 1] = ex + a0;
  // reset deg for use as cursor
  deg[tid] = 0;
  deg[tid + 256] = 0;
  __syncthreads();

  const int nNodes = min(BNODES, n - nodeBase);
  for (int i = tid; i < nNodes; i += 256) offs[nodeBase + i] = cbase + pre[i];

  for (int i = tid; i < cnt; i += 256) {
    int v = gsrc[i];
    int dl = v >> 17;
    int p = pre[dl] + atomicAdd(&deg[dl], 1);
    stage[p] = v & 0x1FFFF;
  }
  __syncthreads();
  for (int i = tid; i < cnt; i += 256) csr[cbase + i] = stage[i];
}

// ---------------------------------------------------------------- GEMM1: X(Nx128) @ W1(128x64) -> H1 sliced [8][n][8] bf16
__global__ __launch_bounds__(256) void k_gemm1(
    const float* __restrict__ A, const float* __restrict__ W1,
    unsigned short* __restrict__ H, int n) {
  __shared__ float Ws[128 * 64];
  for (int t = threadIdx.x; t < 128 * 64; t += 256) Ws[t] = W1[t];
  __syncthreads();

  const int rg = threadIdx.x >> 4;
  const int c0 = (threadIdx.x & 15) * 4;
  const int row0 = blockIdx.x * 64 + rg * 4;

  float acc[4][4] = {};
  for (int k = 0; k < 128; k += 4) {
    float4 a[4];
#pragma unroll
    for (int r = 0; r < 4; ++r) {
      int row = row0 + r;
      int rowc = row < n ? row : n - 1;
      a[r] = *(const float4*)&A[(size_t)rowc * 128 + k];
    }
    float4 w0 = *(const float4*)&Ws[(k + 0) * 64 + c0];
    float4 w1 = *(const float4*)&Ws[(k + 1) * 64 + c0];
    float4 w2 = *(const float4*)&Ws[(k + 2) * 64 + c0];
    float4 w3 = *(const float4*)&Ws[(k + 3) * 64 + c0];
#pragma unroll
    for (int r = 0; r < 4; ++r) {
      acc[r][0] += a[r].x * w0.x + a[r].y * w1.x + a[r].z * w2.x + a[r].w * w3.x;
      acc[r][1] += a[r].x * w0.y + a[r].y * w1.y + a[r].z * w2.y + a[r].w * w3.y;
      acc[r][2] += a[r].x * w0.z + a[r].y * w1.z + a[r].z * w2.z + a[r].w * w3.z;
      acc[r][3] += a[r].x * w0.w + a[r].y * w1.w + a[r].z * w2.w + a[r].w * w3.w;
    }
  }
  const int slice = c0 >> 3;
  const int k0 = c0 & 7;
#pragma unroll
  for (int r = 0; r < 4; ++r) {
    int row = row0 + r;
    if (row < n) {
      ushort4 o;
      o.x = f2bf(acc[r][0]); o.y = f2bf(acc[r][1]);
      o.z = f2bf(acc[r][2]); o.w = f2bf(acc[r][3]);
      *(ushort4*)&H[((size_t)slice * n + row) * 8 + k0] = o;
    }
  }
}

// ---------------------------------------------------------------- hop at D=64, XCD-sliced [8][n][8] bf16
// slice = blockIdx & 7 -> all blocks of slice s land on XCD s (round-robin
// dispatch heuristic): the 1.6 MB slice lives in that XCD's L2 -> gathers hit L2.
// lane = (node, slice); serial edge loop, 8 fp32 accumulators, no reduction.
__global__ __launch_bounds__(256) void k_hop64s(const unsigned short* __restrict__ hin,
    unsigned short* __restrict__ hout, const int* __restrict__ offs,
    const int* __restrict__ csr, int n) {
  const int slice = blockIdx.x & 7;
  const int node = (blockIdx.x >> 3) * 256 + threadIdx.x;
  if (node >= n) return;
  const unsigned short* hs = hin + (size_t)slice * n * 8;
  int beg = offs[node], end = offs[node + 1];
  float a[8] = {};
  acc8(*(const uint4*)&hs[(size_t)node * 8], a);   // self (unit diagonal)
  int e = beg;
  for (; e + 1 < end; e += 2) {
    int i0 = csr[e], i1 = csr[e + 1];
    uint4 v0 = *(const uint4*)&hs[(size_t)i0 * 8];
    uint4 v1 = *(const uint4*)&hs[(size_t)i1 * 8];
    acc8(v0, a);
    acc8(v1, a);
  }
  if (e < end) acc8(*(const uint4*)&hs[(size_t)csr[e] * 8], a);
  *(uint4*)&hout[((size_t)slice * n + node) * 8] = pack8(a);
}

// ---------------------------------------------------------------- batch stats over sliced h3 (streaming)
__global__ __launch_bounds__(256) void k_stats(const unsigned short* __restrict__ h,
    float* __restrict__ stats, int n) {
  const int s = threadIdx.x >> 5;   // slice 0..7
  const int r = threadIdx.x & 31;   // 32 partials per slice
  const unsigned short* hs = h + (size_t)s * n * 8;
  float s1[8] = {}, s2[8] = {};
  for (int i = blockIdx.x * 32 + r; i < n; i += gridDim.x * 32) {
    uint4 v = *(const uint4*)&hs[(size_t)i * 8];
    unsigned int w[4] = {v.x, v.y, v.z, v.w};
#pragma unroll
    for (int j = 0; j < 4; ++j) {
      float lo = __uint_as_float(w[j] << 16);
      float hi = __uint_as_float(w[j] & 0xFFFF0000u);
      s1[2 * j] += lo;     s2[2 * j] += lo * lo;
      s1[2 * j + 1] += hi; s2[2 * j + 1] += hi * hi;
    }
  }
  __shared__ float l1[256][8];
  __shared__ float l2[256][8];
#pragma unroll
  for (int k = 0; k < 8; ++k) { l1[threadIdx.x][k] = s1[k]; l2[threadIdx.x][k] = s2[k]; }
  __syncthreads();
  if (threadIdx.x < 64) {
    int f = threadIdx.x;          // global dim
    int fs = f >> 3, fk = f & 7;
    float t1 = 0.f, t2 = 0.f;
#pragma unroll 8
    for (int j = 0; j < 32; ++j) {
      t1 += l1[fs * 32 + j][fk];
      t2 += l2[fs * 32 + j][fk];
    }
    float* slot = stats + (size_t)(blockIdx.x & (NSLOT - 1)) * 128;
    atomicAdd(&slot[f], t1);
    atomicAdd(&slot[64 + f], t2);
  }
}

__global__ void k_finalize_stats(const float* __restrict__ stats,
    const float* __restrict__ bn_w, const float* __restrict__ bn_b,
    float* __restrict__ ab, int n) {
  int f = threadIdx.x;
  if (f < 64) {
    float s1 = 0.f, s2 = 0.f;
#pragma unroll 4
    for (int j = 0; j < NSLOT; ++j) {
      s1 += stats[(size_t)j * 128 + f];
      s2 += stats[(size_t)j * 128 + 64 + f];
    }
    float inv_n = 1.0f / (float)n;
    float mu = s1 * inv_n;
    float var = s2 * inv_n - mu * mu;
    float s = bn_w[f] * rsqrtf(var + 1e-5f);
    ab[f] = s;
    ab[64 + f] = bn_b[f] - mu * s;
  }
}

// ---------------------------------------------------------------- GEMM2 (sliced bf16 in) + BN affine + SELU -> Y bf16 (Nx16)
__global__ __launch_bounds__(256) void k_gemm2(const unsigned short* __restrict__ A,
    const float* __restrict__ ab, const float* __restrict__ W2,
    unsigned short* __restrict__ Y, int n) {
  int row = blockIdx.x * 256 + threadIdx.x;
  if (row >= n) return;
  float4 acc0 = make_float4(0, 0, 0, 0), acc1 = acc0, acc2 = acc0, acc3 = acc0;
#pragma unroll
  for (int kb = 0; kb < 8; ++kb) {
    uint4 a = *(const uint4*)&A[((size_t)kb * n + row) * 8];
    unsigned int pk[4] = {a.x, a.y, a.z, a.w};
#pragma unroll
    for (int q = 0; q < 8; ++q) {
      int k = kb * 8 + q;
      unsigned int word = pk[q >> 1];
      float f = bf2f((unsigned short)((q & 1) ? (word >> 16) : (word & 0xFFFFu)));
      float y = ab[k] * f + ab[64 + k];
      y = y > 0.f ? SELU_LAMBDA * y : SELU_LAMBDA * SELU_ALPHA * expm1f(y);
      const float4* Wr = (const float4*)&W2[k * 16];
      float4 w0 = Wr[0], w1 = Wr[1], w2 = Wr[2], w3 = Wr[3];
      acc0.x += y * w0.x; acc0.y += y * w0.y; acc0.z += y * w0.z; acc0.w += y * w0.w;
      acc1.x += y * w1.x; acc1.y += y * w1.y; acc1.z += y * w1.z; acc1.w += y * w1.w;
      acc2.x += y * w2.x; acc2.y += y * w2.y; acc2.z += y * w2.z; acc2.w += y * w2.w;
      acc3.x += y * w3.x; acc3.y += y * w3.y; acc3.z += y * w3.z; acc3.w += y * w3.w;
    }
  }
  ushort4 o0, o1, o2, o3;
  o0.x = f2bf(acc0.x); o0.y = f2bf(acc0.y); o0.z = f2bf(acc0.z); o0.w = f2bf(acc0.w);
  o1.x = f2bf(acc1.x); o1.y = f2bf(acc1.y); o1.z = f2bf(acc1.z); o1.w = f2bf(acc1.w);
  o2.x = f2bf(acc2.x); o2.y = f2bf(acc2.y); o2.z = f2bf(acc2.z); o2.w = f2bf(acc2.w);
  o3.x = f2bf(acc3.x); o3.y = f2bf(acc3.y); o3.z = f2bf(acc3.z); o3.w = f2bf(acc3.w);
  ushort4* o = (ushort4*)(Y + (size_t)row * 16);
  o[0] = o0; o[1] = o1; o[2] = o2; o[3] = o3;
}

// ---------------------------------------------------------------- hop at D=16 + b2 + log_softmax
// lane = node; Y (3.2 MB) is L2-replicable across XCDs; softmax fully in-lane.
__global__ __launch_bounds__(256) void k_hop16(const unsigned short* __restrict__ Y,
    const float* __restrict__ b2, float* __restrict__ out,
    const int* __restrict__ offs, const int* __restrict__ csr, int n) {
  int node = blockIdx.x * 256 + threadIdx.x;
  if (node >= n) return;
  int beg = offs[node], end = offs[node + 1];
  float a[16] = {};
  int e = beg;
  for (; e + 1 < end; e += 2) {
    int i0 = csr[e], i1 = csr[e + 1];
    const uint4* r0 = (const uint4*)&Y[(size_t)i0 * 16];
    const uint4* r1 = (const uint4*)&Y[(size_t)i1 * 16];
    uint4 p0 = r0[0], q0 = r0[1];
    uint4 p1 = r1[0], q1 = r1[1];
    acc8(p0, a); acc8(q0, a + 8);
    acc8(p1, a); acc8(q1, a + 8);
  }
  if (e < end) {
    const uint4* r = (const uint4*)&Y[(size_t)csr[e] * 16];
    acc8(r[0], a); acc8(r[1], a + 8);
  }
  const uint4* rs = (const uint4*)&Y[(size_t)node * 16];
  acc8(rs[0], a); acc8(rs[1], a + 8);
#pragma unroll
  for (int k = 0; k < 16; ++k) a[k] += b2[k];
  float m = a[0];
#pragma unroll
  for (int k = 1; k < 16; ++k) m = fmaxf(m, a[k]);
  float ssum = 0.f;
#pragma unroll
  for (int k = 0; k < 16; ++k) ssum += expf(a[k] - m);
  float ls = m + logf(ssum);
  float4* o = (float4*)(out + (size_t)node * 16);
  o[0] = make_float4(a[0] - ls, a[1] - ls, a[2] - ls, a[3] - ls);
  o[1] = make_float4(a[4] - ls, a[5] - ls, a[6] - ls, a[7] - ls);
  o[2] = make_float4(a[8] - ls, a[9] - ls, a[10] - ls, a[11] - ls);
  o[3] = make_float4(a[12] - ls, a[13] - ls, a[14] - ls, a[15] - ls);
}

// ---------------------------------------------------------------- launch
extern "C" void kernel_launch(void* const* d_in, const int* in_sizes, int n_in,
                              void* d_out, int out_size, void* d_ws, size_t ws_size,
                              hipStream_t stream) {
  const float* x   = (const float*)d_in[0];
  const int* esrc  = (const int*)d_in[1];
  const int* edst  = (const int*)d_in[2];
  const float* W1  = (const float*)d_in[3];
  // d_in[4] = b1: cancels exactly under batchnorm mean subtraction
  const float* bnw = (const float*)d_in[5];
  const float* bnb = (const float*)d_in[6];
  const float* W2  = (const float*)d_in[7];
  const float* b2  = (const float*)d_in[8];
  float* out = (float*)d_out;

  const int N = in_sizes[0] / 128;  // 100000
  const int E = in_sizes[1];        // 1600000
  const int NB = (N + BNODES - 1) >> BSHIFT;  // 196 buckets

  char* p = (char*)d_ws;
  auto alloc = [&](size_t bytes) {
    char* q = p;
    p += (bytes + 255) & ~(size_t)255;
    return q;
  };
  int* cursor  = (int*)alloc(256 * sizeof(int));
  int* binned  = (int*)alloc((size_t)NB * CAP * sizeof(int));
  int* offs    = (int*)alloc((size_t)(N + 4) * sizeof(int));
  int* csr     = (int*)alloc((size_t)E * sizeof(int));
  float* stats = (float*)alloc((size_t)NSLOT * 128 * sizeof(float));
  float* ab    = (float*)alloc(128 * sizeof(float));
  unsigned short* h1 = (unsigned short*)alloc((size_t)N * 64 * sizeof(unsigned short));
  unsigned short* h2 = (unsigned short*)alloc((size_t)N * 64 * sizeof(unsigned short));
  unsigned short* h3 = (unsigned short*)alloc((size_t)N * 64 * sizeof(unsigned short));
  unsigned short* Yb = (unsigned short*)alloc((size_t)N * 16 * sizeof(unsigned short));

  k_zero<<<(NSLOT * 128 + 255) / 256, 256, 0, stream>>>(cursor, stats);

  // CSR build: bin -> per-bucket build
  k_bin<<<(E + CHUNK - 1) / CHUNK, 256, 0, stream>>>(esrc, edst, cursor, binned, E);
  k_build<<<NB, 256, 0, stream>>>(binned, cursor, offs, csr, N, NB, E);

  // GEMM first (propagation commutes with the linear layer): hops at D=64 bf16, sliced
  k_gemm1<<<(N + 63) / 64, 256, 0, stream>>>(x, W1, h1, N);

  const int chunks = (N + 255) / 256;
  k_hop64s<<<chunks * 8, 256, 0, stream>>>(h1, h2, offs, csr, N);
  k_hop64s<<<chunks * 8, 256, 0, stream>>>(h2, h3, offs, csr, N);

  k_stats<<<256, 256, 0, stream>>>(h3, stats, N);
  k_finalize_stats<<<1, 64, 0, stream>>>(stats, bnw, bnb, ab, N);

  // GEMM2 (with fused BN+SELU) before the last hop: hop runs at D=16 bf16
  k_gemm2<<<chunks, 256, 0, stream>>>(h3, ab, W2, Yb, N);
  k_hop16<<<chunks, 256, 0, stream>>>(Yb, b2, out, offs, csr, N);
}

// Round 11
// 240.800 us; speedup vs baseline: 1.2792x; 1.2792x over previous
//
#include <hip/hip_runtime.h>
#include <hip/hip_fp16.h>
#include <math.h>

#define SELU_LAMBDA 1.0507009873554805f
#define SELU_ALPHA  1.6732632423543772f

#define BSHIFT 9
#define BNODES 512          // nodes per bucket
#define CAP    10240        // bucket capacity (mean 8192, +22 sigma)
#define CHUNK  4096         // edges per k_bin block
#define NSLOT  64           // stats atomic spreading slots

// fp16 helpers (h buffers are fp16: better mantissa than bf16, range is ample)
__device__ __forceinline__ unsigned int f2h2(float a, float b) {
  __half2 h = __floats2half2_rn(a, b);
  return *(unsigned int*)&h;
}
__device__ __forceinline__ float2 h22f2(unsigned int u) {
  __half2 h = *(__half2*)&u;
  return __half22float2(h);
}
__device__ __forceinline__ unsigned int hadd2(unsigned int a, unsigned int b) {
  __half2 x = *(__half2*)&a, y = *(__half2*)&b;
  __half2 r = __hadd2(x, y);
  return *(unsigned int*)&r;
}

// ---------------------------------------------------------------- setup: zero cursor/stats/pad rows
__global__ __launch_bounds__(256) void k_zero(int* __restrict__ cursor,
    float* __restrict__ stats, unsigned short* __restrict__ h1pad,
    unsigned short* __restrict__ h2pad, unsigned short* __restrict__ ybpad) {
  int i = blockIdx.x * 256 + threadIdx.x;
  if (i < 256) cursor[i] = 0;
  if (i < NSLOT * 128) stats[i] = 0.f;
  if (i < 64) { h1pad[i] = 0; h2pad[i] = 0; }
  if (i < 16) ybpad[i] = 0;
}

// ---------------------------------------------------------------- phase 1: bin edges by dst bucket
// packed entry: src | (dstLocal << 17)   (src < 2^17, dstLocal < 2^9)
__global__ __launch_bounds__(256) void k_bin(const int* __restrict__ src,
    const int* __restrict__ dst, int* __restrict__ cursor,
    int* __restrict__ binned, int e) {
  __shared__ int hist[256];
  __shared__ int gb[256];
  const int tid = threadIdx.x;
  hist[tid] = 0;
  __syncthreads();
  const int base = blockIdx.x * CHUNK;
  int bk[16], rk[16], pk[16];
#pragma unroll
  for (int k = 0; k < 16; ++k) {
    int i = base + k * 256 + tid;
    if (i < e) {
      int d = dst[i];
      int s = src[i];
      int b = d >> BSHIFT;
      bk[k] = b;
      pk[k] = s | ((d & (BNODES - 1)) << 17);
      rk[k] = atomicAdd(&hist[b], 1);
    } else {
      bk[k] = -1;
    }
  }
  __syncthreads();
  int h = hist[tid];
  if (h > 0) gb[tid] = atomicAdd(&cursor[tid], h);
  __syncthreads();
#pragma unroll
  for (int k = 0; k < 16; ++k) {
    if (bk[k] >= 0) binned[bk[k] * CAP + gb[bk[k]] + rk[k]] = pk[k];
  }
}

// ---------------------------------------------------------------- phase 2: per-bucket CSR build (one wg owns one bucket)
__global__ __launch_bounds__(256) void k_build(const int* __restrict__ binned,
    const int* __restrict__ cursor, int* __restrict__ offs,
    int* __restrict__ csr, int n, int nb, int etot) {
  __shared__ int sc[2][256];
  __shared__ int deg[BNODES];
  __shared__ int pre[BNODES];
  __shared__ int wsum[4];
  __shared__ int stage[CAP];
  __shared__ int s_cbase;
  const int b = blockIdx.x;
  const int tid = threadIdx.x;

  // replicated inclusive scan of the nb bucket counts
  int v0 = (tid < nb) ? cursor[tid] : 0;
  sc[0][tid] = v0;
  __syncthreads();
  int cur = 0;
  for (int d = 1; d < 256; d <<= 1) {
    int t = sc[cur][tid];
    if (tid >= d) t += sc[cur][tid - d];
    sc[cur ^ 1][tid] = t;
    cur ^= 1;
    __syncthreads();
  }
  if (tid == 0) {
    s_cbase = (b == 0) ? 0 : sc[cur][b - 1];
    if (b == 0) offs[n] = etot;
  }
  deg[tid] = 0;
  deg[tid + 256] = 0;
  __syncthreads();
  const int cbase = s_cbase;
  const int cnt = sc[cur][b] - cbase;

  const int nodeBase = b << BSHIFT;
  const int* gsrc = binned + b * CAP;

  for (int i = tid; i < cnt; i += 256) atomicAdd(&deg[gsrc[i] >> 17], 1);
  __syncthreads();

  // exclusive scan of deg[512]: 2 elements/thread
  const int lane = tid & 63, w = tid >> 6;
  int a0 = deg[2 * tid], a1 = deg[2 * tid + 1];
  int ps = a0 + a1;
  int s = ps;
#pragma unroll
  for (int d = 1; d < 64; d <<= 1) {
    int t = __shfl_up(s, d, 64);
    if (lane >= d) s += t;
  }
  if (lane == 63) wsum[w] = s;
  __syncthreads();
  if (tid == 0) {
    int acc = 0;
#pragma unroll
    for (int j = 0; j < 4; ++j) { int t = wsum[j]; wsum[j] = acc; acc += t; }
  }
  __syncthreads();
  int ex = wsum[w] + s - ps;
  pre[2 * tid] = ex;
  pre[2 * tid + 1] = ex + a0;
  // reset deg for use as cursor
  deg[tid] = 0;
  deg[tid + 256] = 0;
  __syncthreads();

  const int nNodes = min(BNODES, n - nodeBase);
  for (int i = tid; i < nNodes; i += 256) offs[nodeBase + i] = cbase + pre[i];

  for (int i = tid; i < cnt; i += 256) {
    int v = gsrc[i];
    int dl = v >> 17;
    int p = pre[dl] + atomicAdd(&deg[dl], 1);
    stage[p] = v & 0x1FFFF;
  }
  __syncthreads();
  for (int i = tid; i < cnt; i += 256) csr[cbase + i] = stage[i];
}

// ---------------------------------------------------------------- GEMM1: X(Nx128) @ W1(128x64) -> H1(Nx64) fp16
__global__ __launch_bounds__(256) void k_gemm1(
    const float* __restrict__ A, const float* __restrict__ W1,
    unsigned short* __restrict__ H, int n) {
  __shared__ float Ws[128 * 64];
  for (int t = threadIdx.x; t < 128 * 64; t += 256) Ws[t] = W1[t];
  __syncthreads();

  const int rg = threadIdx.x >> 4;
  const int c0 = (threadIdx.x & 15) * 4;
  const int row0 = blockIdx.x * 64 + rg * 4;

  float acc[4][4] = {};
  for (int k = 0; k < 128; k += 4) {
    float4 a[4];
#pragma unroll
    for (int r = 0; r < 4; ++r) {
      int row = row0 + r;
      int rowc = row < n ? row : n - 1;
      a[r] = *(const float4*)&A[(size_t)rowc * 128 + k];
    }
    float4 w0 = *(const float4*)&Ws[(k + 0) * 64 + c0];
    float4 w1 = *(const float4*)&Ws[(k + 1) * 64 + c0];
    float4 w2 = *(const float4*)&Ws[(k + 2) * 64 + c0];
    float4 w3 = *(const float4*)&Ws[(k + 3) * 64 + c0];
#pragma unroll
    for (int r = 0; r < 4; ++r) {
      acc[r][0] += a[r].x * w0.x + a[r].y * w1.x + a[r].z * w2.x + a[r].w * w3.x;
      acc[r][1] += a[r].x * w0.y + a[r].y * w1.y + a[r].z * w2.y + a[r].w * w3.y;
      acc[r][2] += a[r].x * w0.z + a[r].y * w1.z + a[r].z * w2.z + a[r].w * w3.z;
      acc[r][3] += a[r].x * w0.w + a[r].y * w1.w + a[r].z * w2.w + a[r].w * w3.w;
    }
  }
#pragma unroll
  for (int r = 0; r < 4; ++r) {
    int row = row0 + r;
    if (row < n) {
      uint2 o;
      o.x = f2h2(acc[r][0], acc[r][1]);
      o.y = f2h2(acc[r][2], acc[r][3]);
      *(uint2*)&H[(size_t)row * 64 + c0] = o;
    }
  }
}

// ---------------------------------------------------------------- hop at D=64 (fp16 in/out)
// one wave per node; 4 sub-groups of 16 lanes; each lane loads 4 dims (8B)
// -> one gather covers 4 edges; packed half2 adds (2 VALU per edge).
// Short batches pad with zero row n.
__device__ __forceinline__ void hop64_gather4h(const unsigned short* __restrict__ hin,
    const int* __restrict__ csr, int beg, int end, int sub, int t, int npad,
    unsigned int& a01, unsigned int& a23) {
  a01 = 0u; a23 = 0u;
  for (int eb = beg; eb < end; eb += 16) {
    int idx[4];
#pragma unroll
    for (int k = 0; k < 4; ++k) {
      int a = eb + k * 4 + sub;
      idx[k] = (a < end) ? csr[a] : npad;   // pad -> zero row, no masking needed
    }
    uint2 v[4];
#pragma unroll
    for (int k = 0; k < 4; ++k)
      v[k] = *(const uint2*)&hin[(size_t)idx[k] * 64 + 4 * t];
#pragma unroll
    for (int k = 0; k < 4; ++k) {
      a01 = hadd2(a01, v[k].x);
      a23 = hadd2(a23, v[k].y);
    }
  }
}

__global__ __launch_bounds__(256) void k_hop64b(const unsigned short* __restrict__ hin,
    unsigned short* __restrict__ hout, const int* __restrict__ offs,
    const int* __restrict__ csr, int n) {
  int wid = (blockIdx.x * 256 + threadIdx.x) >> 6;
  if (wid >= n) return;
  int lane = threadIdx.x & 63;
  int sub = lane >> 4, t = lane & 15;
  int beg = offs[wid], end = offs[wid + 1];
  unsigned int a01, a23;
  hop64_gather4h(hin, csr, beg, end, sub, t, n, a01, a23);
  a01 = hadd2(a01, (unsigned int)__shfl_down((int)a01, 32, 64));
  a23 = hadd2(a23, (unsigned int)__shfl_down((int)a23, 32, 64));
  a01 = hadd2(a01, (unsigned int)__shfl_down((int)a01, 16, 64));
  a23 = hadd2(a23, (unsigned int)__shfl_down((int)a23, 16, 64));
  if (sub == 0) {
    uint2 sv = *(const uint2*)&hin[(size_t)wid * 64 + 4 * t];
    uint2 o;
    o.x = hadd2(a01, sv.x);
    o.y = hadd2(a23, sv.y);
    *(uint2*)&hout[(size_t)wid * 64 + 4 * t] = o;
  }
}

// hop2: fp16 in/out, fused per-column (sum, sumsq) batch stats (fp32 epilogue)
__global__ __launch_bounds__(256) void k_hop64b_stats(const unsigned short* __restrict__ hin,
    unsigned short* __restrict__ hout, const int* __restrict__ offs,
    const int* __restrict__ csr, float* __restrict__ stats, int n) {
  int wid = (blockIdx.x * 256 + threadIdx.x) >> 6;
  int lane = threadIdx.x & 63;
  int sub = lane >> 4, t = lane & 15;
  float f0 = 0.f, f1 = 0.f, f2 = 0.f, f3 = 0.f;
  if (wid < n) {
    int beg = offs[wid], end = offs[wid + 1];
    unsigned int a01, a23;
    hop64_gather4h(hin, csr, beg, end, sub, t, n, a01, a23);
    a01 = hadd2(a01, (unsigned int)__shfl_down((int)a01, 32, 64));
    a23 = hadd2(a23, (unsigned int)__shfl_down((int)a23, 32, 64));
    a01 = hadd2(a01, (unsigned int)__shfl_down((int)a01, 16, 64));
    a23 = hadd2(a23, (unsigned int)__shfl_down((int)a23, 16, 64));
    if (sub == 0) {
      uint2 sv = *(const uint2*)&hin[(size_t)wid * 64 + 4 * t];
      uint2 o;
      o.x = hadd2(a01, sv.x);
      o.y = hadd2(a23, sv.y);
      *(uint2*)&hout[(size_t)wid * 64 + 4 * t] = o;
      float2 p01 = h22f2(o.x), p23 = h22f2(o.y);
      f0 = p01.x; f1 = p01.y; f2 = p23.x; f3 = p23.y;
    }
  }
  __shared__ float l1[4][64];
  __shared__ float l2[4][64];
  const int w = threadIdx.x >> 6;
  if (sub == 0) {
    *(float4*)&l1[w][4 * t] = make_float4(f0, f1, f2, f3);
    *(float4*)&l2[w][4 * t] = make_float4(f0 * f0, f1 * f1, f2 * f2, f3 * f3);
  }
  __syncthreads();
  if (threadIdx.x < 64) {
    float t1 = l1[0][threadIdx.x] + l1[1][threadIdx.x] + l1[2][threadIdx.x] + l1[3][threadIdx.x];
    float t2 = l2[0][threadIdx.x] + l2[1][threadIdx.x] + l2[2][threadIdx.x] + l2[3][threadIdx.x];
    float* slot = stats + (size_t)(blockIdx.x & (NSLOT - 1)) * 128;
    atomicAdd(&slot[threadIdx.x], t1);
    atomicAdd(&slot[64 + threadIdx.x], t2);
  }
}

__global__ void k_finalize_stats(const float* __restrict__ stats,
    const float* __restrict__ bn_w, const float* __restrict__ bn_b,
    float* __restrict__ ab, int n) {
  int f = threadIdx.x;
  if (f < 64) {
    float s1 = 0.f, s2 = 0.f;
#pragma unroll 4
    for (int j = 0; j < NSLOT; ++j) {
      s1 += stats[(size_t)j * 128 + f];
      s2 += stats[(size_t)j * 128 + 64 + f];
    }
    float inv_n = 1.0f / (float)n;
    float mu = s1 * inv_n;
    float var = s2 * inv_n - mu * mu;
    float s = bn_w[f] * rsqrtf(var + 1e-5f);
    ab[f] = s;
    ab[64 + f] = bn_b[f] - mu * s;
  }
}

// ---------------------------------------------------------------- GEMM2 (fp16 in) with fused BN affine + SELU -> Y fp16 (Nx16)
__global__ __launch_bounds__(256) void k_gemm2(const unsigned short* __restrict__ A,
    const float* __restrict__ ab, const float* __restrict__ W2,
    unsigned short* __restrict__ Y, int n) {
  int row = blockIdx.x * 256 + threadIdx.x;
  if (row >= n) return;
  float4 acc0 = make_float4(0, 0, 0, 0), acc1 = acc0, acc2 = acc0, acc3 = acc0;
  const uint4* A4 = (const uint4*)(A + (size_t)row * 64);
#pragma unroll
  for (int kb = 0; kb < 8; ++kb) {
    uint4 a = A4[kb];
    unsigned int pk[4] = {a.x, a.y, a.z, a.w};
#pragma unroll
    for (int q = 0; q < 4; ++q) {
      float2 f2v = h22f2(pk[q]);
#pragma unroll
      for (int h = 0; h < 2; ++h) {
        int k = kb * 8 + 2 * q + h;
        float f = h ? f2v.y : f2v.x;
        float y = ab[k] * f + ab[64 + k];
        y = y > 0.f ? SELU_LAMBDA * y : SELU_LAMBDA * SELU_ALPHA * expm1f(y);
        const float4* Wr = (const float4*)&W2[k * 16];
        float4 w0 = Wr[0], w1 = Wr[1], w2 = Wr[2], w3 = Wr[3];
        acc0.x += y * w0.x; acc0.y += y * w0.y; acc0.z += y * w0.z; acc0.w += y * w0.w;
        acc1.x += y * w1.x; acc1.y += y * w1.y; acc1.z += y * w1.z; acc1.w += y * w1.w;
        acc2.x += y * w2.x; acc2.y += y * w2.y; acc2.z += y * w2.z; acc2.w += y * w2.w;
        acc3.x += y * w3.x; acc3.y += y * w3.y; acc3.z += y * w3.z; acc3.w += y * w3.w;
      }
    }
  }
  uint4 o;
  o.x = f2h2(acc0.x, acc0.y); o.y = f2h2(acc0.z, acc0.w);
  o.z = f2h2(acc1.x, acc1.y); o.w = f2h2(acc1.z, acc1.w);
  uint4 o2;
  o2.x = f2h2(acc2.x, acc2.y); o2.y = f2h2(acc2.z, acc2.w);
  o2.z = f2h2(acc3.x, acc3.y); o2.w = f2h2(acc3.z, acc3.w);
  uint4* op = (uint4*)(Y + (size_t)row * 16);
  op[0] = o;
  op[1] = o2;
}

// ---------------------------------------------------------------- hop at D=16 (fp16 in) + b2 + log_softmax
// one wave per node; 8 subgroups x 8 lanes; lane loads uint (2 dims, half2)
// -> one gather covers 8 edges, 1 packed add per edge. Pad with zero row n.
__global__ __launch_bounds__(256) void k_hop16(const unsigned short* __restrict__ Y,
    const float* __restrict__ b2, float* __restrict__ out,
    const int* __restrict__ offs, const int* __restrict__ csr, int n) {
  int wid = (blockIdx.x * 256 + threadIdx.x) >> 6;
  if (wid >= n) return;
  int lane = threadIdx.x & 63;
  int sub = lane >> 3, t = lane & 7;   // lane covers dims 2t, 2t+1
  int beg = offs[wid], end = offs[wid + 1];
  unsigned int accp = 0u;
  for (int eb = beg; eb < end; eb += 8) {
    int a = eb + sub;
    int idx = (a < end) ? csr[a] : n;   // row n = zero pad
    accp = hadd2(accp, *(const unsigned int*)&Y[(size_t)idx * 16 + 2 * t]);
  }
  // fp16 partials -> fp32 for the cross-subgroup reduction and softmax
  float2 pf = h22f2(accp);
  float a0 = pf.x, a1 = pf.y;
  a0 += __shfl_down(a0, 32, 64); a1 += __shfl_down(a1, 32, 64);
  a0 += __shfl_down(a0, 16, 64); a1 += __shfl_down(a1, 16, 64);
  a0 += __shfl_down(a0, 8, 64);  a1 += __shfl_down(a1, 8, 64);
  if (sub == 0) {
    float2 sf = h22f2(*(const unsigned int*)&Y[(size_t)wid * 16 + 2 * t]);
    float2 bb = *(const float2*)&b2[2 * t];
    float v0 = a0 + sf.x + bb.x;
    float v1 = a1 + sf.y + bb.y;
    float m = fmaxf(v0, v1);
#pragma unroll
    for (int d = 4; d >= 1; d >>= 1) m = fmaxf(m, __shfl_xor(m, d, 8));
    float s = expf(v0 - m) + expf(v1 - m);
#pragma unroll
    for (int d = 4; d >= 1; d >>= 1) s += __shfl_xor(s, d, 8);
    float ls = m + logf(s);
    *(float2*)&out[(size_t)wid * 16 + 2 * t] = make_float2(v0 - ls, v1 - ls);
  }
}

// ---------------------------------------------------------------- launch
extern "C" void kernel_launch(void* const* d_in, const int* in_sizes, int n_in,
                              void* d_out, int out_size, void* d_ws, size_t ws_size,
                              hipStream_t stream) {
  const float* x   = (const float*)d_in[0];
  const int* esrc  = (const int*)d_in[1];
  const int* edst  = (const int*)d_in[2];
  const float* W1  = (const float*)d_in[3];
  // d_in[4] = b1: cancels exactly under batchnorm mean subtraction
  const float* bnw = (const float*)d_in[5];
  const float* bnb = (const float*)d_in[6];
  const float* W2  = (const float*)d_in[7];
  const float* b2  = (const float*)d_in[8];
  float* out = (float*)d_out;

  const int N = in_sizes[0] / 128;  // 100000
  const int E = in_sizes[1];        // 1600000
  const int NB = (N + BNODES - 1) >> BSHIFT;  // 196 buckets

  char* p = (char*)d_ws;
  auto alloc = [&](size_t bytes) {
    char* q = p;
    p += (bytes + 255) & ~(size_t)255;
    return q;
  };
  int* cursor  = (int*)alloc(256 * sizeof(int));
  int* binned  = (int*)alloc((size_t)NB * CAP * sizeof(int));
  int* offs    = (int*)alloc((size_t)(N + 4) * sizeof(int));
  int* csr     = (int*)alloc((size_t)E * sizeof(int));
  float* stats = (float*)alloc((size_t)NSLOT * 128 * sizeof(float));
  float* ab    = (float*)alloc(128 * sizeof(float));
  unsigned short* h1 = (unsigned short*)alloc((size_t)(N + 1) * 64 * sizeof(unsigned short));
  unsigned short* h2 = (unsigned short*)alloc((size_t)(N + 1) * 64 * sizeof(unsigned short));
  unsigned short* h3 = (unsigned short*)alloc((size_t)N * 64 * sizeof(unsigned short));
  unsigned short* Yb = (unsigned short*)alloc((size_t)(N + 1) * 16 * sizeof(unsigned short));

  // one setup kernel zeroes cursor, stats, and the three zero-pad rows
  k_zero<<<(NSLOT * 128 + 255) / 256, 256, 0, stream>>>(
      cursor, stats, h1 + (size_t)N * 64, h2 + (size_t)N * 64, Yb + (size_t)N * 16);

  // CSR build: bin -> per-bucket build (bucket scan folded into k_build)
  k_bin<<<(E + CHUNK - 1) / CHUNK, 256, 0, stream>>>(esrc, edst, cursor, binned, E);
  k_build<<<NB, 256, 0, stream>>>(binned, cursor, offs, csr, N, NB, E);

  // GEMM first (propagation commutes with the linear layer): hops run at D=64 fp16
  k_gemm1<<<(N + 63) / 64, 256, 0, stream>>>(x, W1, h1, N);

  int hopBlocks = (N * 64 + 255) / 256;  // one wave per node
  k_hop64b<<<hopBlocks, 256, 0, stream>>>(h1, h2, offs, csr, N);
  k_hop64b_stats<<<hopBlocks, 256, 0, stream>>>(h2, h3, offs, csr, stats, N);

  k_finalize_stats<<<1, 64, 0, stream>>>(stats, bnw, bnb, ab, N);

  // GEMM2 (with fused BN+SELU) before the last hop: hop runs at D=16 fp16
  k_gemm2<<<(N + 255) / 256, 256, 0, stream>>>(h3, ab, W2, Yb, N);
  k_hop16<<<hopBlocks, 256, 0, stream>>>(Yb, b2, out, offs, csr, N);
}

// Round 12
// 224.421 us; speedup vs baseline: 1.3726x; 1.0730x over previous
//
#include <hip/hip_runtime.h>
#include <hip/hip_fp16.h>
#include <math.h>

#define SELU_LAMBDA 1.0507009873554805f
#define SELU_ALPHA  1.6732632423543772f

#define BSHIFT 9
#define BNODES 512          // nodes per bucket
#define CAP    10240        // bucket capacity (mean 8192, +22 sigma)
#define CHUNK  4096         // edges per k_bin block
#define NSLOT  64           // stats atomic spreading slots

typedef _Float16 half8 __attribute__((ext_vector_type(8)));
typedef float f32x4 __attribute__((ext_vector_type(4)));

// fp16 helpers (h buffers are fp16: better mantissa than bf16, range is ample)
__device__ __forceinline__ unsigned int f2h2(float a, float b) {
  __half2 h = __floats2half2_rn(a, b);
  return *(unsigned int*)&h;
}
__device__ __forceinline__ float2 h22f2(unsigned int u) {
  __half2 h = *(__half2*)&u;
  return __half22float2(h);
}
__device__ __forceinline__ unsigned int hadd2(unsigned int a, unsigned int b) {
  __half2 x = *(__half2*)&a, y = *(__half2*)&b;
  __half2 r = __hadd2(x, y);
  return *(unsigned int*)&r;
}

// ---------------------------------------------------------------- setup: zero cursor/stats/pad rows
__global__ __launch_bounds__(256) void k_zero(int* __restrict__ cursor,
    float* __restrict__ stats, unsigned short* __restrict__ h1pad,
    unsigned short* __restrict__ h2pad, unsigned short* __restrict__ ybpad) {
  int i = blockIdx.x * 256 + threadIdx.x;
  if (i < 256) cursor[i] = 0;
  if (i < NSLOT * 128) stats[i] = 0.f;
  if (i < 64) { h1pad[i] = 0; h2pad[i] = 0; }
  if (i < 16) ybpad[i] = 0;
}

// ---------------------------------------------------------------- phase 1: bin edges by dst bucket
// packed entry: src | (dstLocal << 17)   (src < 2^17, dstLocal < 2^9)
__global__ __launch_bounds__(256) void k_bin(const int* __restrict__ src,
    const int* __restrict__ dst, int* __restrict__ cursor,
    int* __restrict__ binned, int e) {
  __shared__ int hist[256];
  __shared__ int gb[256];
  const int tid = threadIdx.x;
  hist[tid] = 0;
  __syncthreads();
  const int base = blockIdx.x * CHUNK;
  int bk[16], rk[16], pk[16];
#pragma unroll
  for (int k = 0; k < 16; ++k) {
    int i = base + k * 256 + tid;
    if (i < e) {
      int d = dst[i];
      int s = src[i];
      int b = d >> BSHIFT;
      bk[k] = b;
      pk[k] = s | ((d & (BNODES - 1)) << 17);
      rk[k] = atomicAdd(&hist[b], 1);
    } else {
      bk[k] = -1;
    }
  }
  __syncthreads();
  int h = hist[tid];
  if (h > 0) gb[tid] = atomicAdd(&cursor[tid], h);
  __syncthreads();
#pragma unroll
  for (int k = 0; k < 16; ++k) {
    if (bk[k] >= 0) binned[bk[k] * CAP + gb[bk[k]] + rk[k]] = pk[k];
  }
}

// ---------------------------------------------------------------- phase 2: per-bucket CSR build (one wg owns one bucket)
__global__ __launch_bounds__(256) void k_build(const int* __restrict__ binned,
    const int* __restrict__ cursor, int* __restrict__ offs,
    int* __restrict__ csr, int n, int nb, int etot) {
  __shared__ int sc[2][256];
  __shared__ int deg[BNODES];
  __shared__ int pre[BNODES];
  __shared__ int wsum[4];
  __shared__ int stage[CAP];
  __shared__ int s_cbase;
  const int b = blockIdx.x;
  const int tid = threadIdx.x;

  // replicated inclusive scan of the nb bucket counts
  int v0 = (tid < nb) ? cursor[tid] : 0;
  sc[0][tid] = v0;
  __syncthreads();
  int cur = 0;
  for (int d = 1; d < 256; d <<= 1) {
    int t = sc[cur][tid];
    if (tid >= d) t += sc[cur][tid - d];
    sc[cur ^ 1][tid] = t;
    cur ^= 1;
    __syncthreads();
  }
  if (tid == 0) {
    s_cbase = (b == 0) ? 0 : sc[cur][b - 1];
    if (b == 0) offs[n] = etot;
  }
  deg[tid] = 0;
  deg[tid + 256] = 0;
  __syncthreads();
  const int cbase = s_cbase;
  const int cnt = sc[cur][b] - cbase;

  const int nodeBase = b << BSHIFT;
  const int* gsrc = binned + b * CAP;

  for (int i = tid; i < cnt; i += 256) atomicAdd(&deg[gsrc[i] >> 17], 1);
  __syncthreads();

  // exclusive scan of deg[512]: 2 elements/thread
  const int lane = tid & 63, w = tid >> 6;
  int a0 = deg[2 * tid], a1 = deg[2 * tid + 1];
  int ps = a0 + a1;
  int s = ps;
#pragma unroll
  for (int d = 1; d < 64; d <<= 1) {
    int t = __shfl_up(s, d, 64);
    if (lane >= d) s += t;
  }
  if (lane == 63) wsum[w] = s;
  __syncthreads();
  if (tid == 0) {
    int acc = 0;
#pragma unroll
    for (int j = 0; j < 4; ++j) { int t = wsum[j]; wsum[j] = acc; acc += t; }
  }
  __syncthreads();
  int ex = wsum[w] + s - ps;
  pre[2 * tid] = ex;
  pre[2 * tid + 1] = ex + a0;
  // reset deg for use as cursor
  deg[tid] = 0;
  deg[tid + 256] = 0;
  __syncthreads();

  const int nNodes = min(BNODES, n - nodeBase);
  for (int i = tid; i < nNodes; i += 256) offs[nodeBase + i] = cbase + pre[i];

  for (int i = tid; i < cnt; i += 256) {
    int v = gsrc[i];
    int dl = v >> 17;
    int p = pre[dl] + atomicAdd(&deg[dl], 1);
    stage[p] = v & 0x1FFFF;
  }
  __syncthreads();
  for (int i = tid; i < cnt; i += 256) csr[cbase + i] = stage[i];
}

// ---------------------------------------------------------------- W1 fragment prep for MFMA gemm1
// Wfrag[(ntile*4+kb)*64+lane] = 8 fp16: element j = W1[kb*32+(lane>>4)*8+j][ntile*16+(lane&15)]
__global__ __launch_bounds__(256) void k_prepW(const float* __restrict__ W1,
    unsigned short* __restrict__ Wfrag) {
  int e = threadIdx.x + blockIdx.x * 256;   // 1024 entries, grid 4x256
  if (e >= 1024) return;
  int lane = e & 63;
  int kb = (e >> 6) & 3;
  int ntile = e >> 8;
  int k0 = kb * 32 + (lane >> 4) * 8;
  int col = ntile * 16 + (lane & 15);
  unsigned short tmp[8];
#pragma unroll
  for (int j = 0; j < 8; ++j) {
    __half h = __float2half_rn(W1[(size_t)(k0 + j) * 64 + col]);
    tmp[j] = *(unsigned short*)&h;
  }
  uint4* o = (uint4*)&Wfrag[(size_t)e * 8];
  *o = *(uint4*)tmp;
}

// ---------------------------------------------------------------- GEMM1 via MFMA: H1 = x @ W1 (fp16 out)
// wave handles 16 rows x 64 cols; D = W1^T-tile (A-op) x x^T-tile (B-op)
// -> C/D lane layout gives 4 consecutive n per lane -> 8B stores.
__global__ __launch_bounds__(256) void k_gemm1(
    const float* __restrict__ A, const unsigned short* __restrict__ Wfrag,
    unsigned short* __restrict__ H, int n) {
  const int lane = threadIdx.x & 63;
  const int wv = threadIdx.x >> 6;
  const int r0 = blockIdx.x * 64 + wv * 16;

  const int brow = r0 + (lane & 15);           // B-frag source row of x
  const int browc = brow < n ? brow : n - 1;
  const float* xrow = A + (size_t)browc * 128 + (lane >> 4) * 8;

  f32x4 acc[4] = {};
#pragma unroll
  for (int kb = 0; kb < 4; ++kb) {
    float4 p = *(const float4*)(xrow + kb * 32);
    float4 q = *(const float4*)(xrow + kb * 32 + 4);
    half8 xf;
    xf[0] = (_Float16)p.x; xf[1] = (_Float16)p.y;
    xf[2] = (_Float16)p.z; xf[3] = (_Float16)p.w;
    xf[4] = (_Float16)q.x; xf[5] = (_Float16)q.y;
    xf[6] = (_Float16)q.z; xf[7] = (_Float16)q.w;
#pragma unroll
    for (int nt = 0; nt < 4; ++nt) {
      half8 wf = *(const half8*)&Wfrag[(size_t)((nt * 4 + kb) * 64 + lane) * 8];
      acc[nt] = __builtin_amdgcn_mfma_f32_16x16x32_f16(wf, xf, acc[nt], 0, 0, 0);
    }
  }
  const int orow = r0 + (lane & 15);
  if (orow < n) {
#pragma unroll
    for (int nt = 0; nt < 4; ++nt) {
      int col = nt * 16 + (lane >> 4) * 4;
      uint2 o;
      o.x = f2h2(acc[nt][0], acc[nt][1]);
      o.y = f2h2(acc[nt][2], acc[nt][3]);
      *(uint2*)&H[(size_t)orow * 64 + col] = o;
    }
  }
}

// ---------------------------------------------------------------- hop at D=64 (fp16 in/out)
// one wave per node; 4 sub-groups of 16 lanes; each lane loads 4 dims (8B)
// -> one gather covers 4 edges; packed half2 adds (2 VALU per edge).
// Short batches pad with zero row n.
__device__ __forceinline__ void hop64_gather4h(const unsigned short* __restrict__ hin,
    const int* __restrict__ csr, int beg, int end, int sub, int t, int npad,
    unsigned int& a01, unsigned int& a23) {
  a01 = 0u; a23 = 0u;
  for (int eb = beg; eb < end; eb += 16) {
    int idx[4];
#pragma unroll
    for (int k = 0; k < 4; ++k) {
      int a = eb + k * 4 + sub;
      idx[k] = (a < end) ? csr[a] : npad;   // pad -> zero row, no masking needed
    }
    uint2 v[4];
#pragma unroll
    for (int k = 0; k < 4; ++k)
      v[k] = *(const uint2*)&hin[(size_t)idx[k] * 64 + 4 * t];
#pragma unroll
    for (int k = 0; k < 4; ++k) {
      a01 = hadd2(a01, v[k].x);
      a23 = hadd2(a23, v[k].y);
    }
  }
}

__global__ __launch_bounds__(256) void k_hop64b(const unsigned short* __restrict__ hin,
    unsigned short* __restrict__ hout, const int* __restrict__ offs,
    const int* __restrict__ csr, int n) {
  int wid = (blockIdx.x * 256 + threadIdx.x) >> 6;
  if (wid >= n) return;
  int lane = threadIdx.x & 63;
  int sub = lane >> 4, t = lane & 15;
  int beg = offs[wid], end = offs[wid + 1];
  unsigned int a01, a23;
  hop64_gather4h(hin, csr, beg, end, sub, t, n, a01, a23);
  a01 = hadd2(a01, (unsigned int)__shfl_down((int)a01, 32, 64));
  a23 = hadd2(a23, (unsigned int)__shfl_down((int)a23, 32, 64));
  a01 = hadd2(a01, (unsigned int)__shfl_down((int)a01, 16, 64));
  a23 = hadd2(a23, (unsigned int)__shfl_down((int)a23, 16, 64));
  if (sub == 0) {
    uint2 sv = *(const uint2*)&hin[(size_t)wid * 64 + 4 * t];
    uint2 o;
    o.x = hadd2(a01, sv.x);
    o.y = hadd2(a23, sv.y);
    *(uint2*)&hout[(size_t)wid * 64 + 4 * t] = o;
  }
}

// hop2: fp16 in/out, fused per-column (sum, sumsq) batch stats (fp32 epilogue)
__global__ __launch_bounds__(256) void k_hop64b_stats(const unsigned short* __restrict__ hin,
    unsigned short* __restrict__ hout, const int* __restrict__ offs,
    const int* __restrict__ csr, float* __restrict__ stats, int n) {
  int wid = (blockIdx.x * 256 + threadIdx.x) >> 6;
  int lane = threadIdx.x & 63;
  int sub = lane >> 4, t = lane & 15;
  float f0 = 0.f, f1 = 0.f, f2 = 0.f, f3 = 0.f;
  if (wid < n) {
    int beg = offs[wid], end = offs[wid + 1];
    unsigned int a01, a23;
    hop64_gather4h(hin, csr, beg, end, sub, t, n, a01, a23);
    a01 = hadd2(a01, (unsigned int)__shfl_down((int)a01, 32, 64));
    a23 = hadd2(a23, (unsigned int)__shfl_down((int)a23, 32, 64));
    a01 = hadd2(a01, (unsigned int)__shfl_down((int)a01, 16, 64));
    a23 = hadd2(a23, (unsigned int)__shfl_down((int)a23, 16, 64));
    if (sub == 0) {
      uint2 sv = *(const uint2*)&hin[(size_t)wid * 64 + 4 * t];
      uint2 o;
      o.x = hadd2(a01, sv.x);
      o.y = hadd2(a23, sv.y);
      *(uint2*)&hout[(size_t)wid * 64 + 4 * t] = o;
      float2 p01 = h22f2(o.x), p23 = h22f2(o.y);
      f0 = p01.x; f1 = p01.y; f2 = p23.x; f3 = p23.y;
    }
  }
  __shared__ float l1[4][64];
  __shared__ float l2[4][64];
  const int w = threadIdx.x >> 6;
  if (sub == 0) {
    *(float4*)&l1[w][4 * t] = make_float4(f0, f1, f2, f3);
    *(float4*)&l2[w][4 * t] = make_float4(f0 * f0, f1 * f1, f2 * f2, f3 * f3);
  }
  __syncthreads();
  if (threadIdx.x < 64) {
    float t1 = l1[0][threadIdx.x] + l1[1][threadIdx.x] + l1[2][threadIdx.x] + l1[3][threadIdx.x];
    float t2 = l2[0][threadIdx.x] + l2[1][threadIdx.x] + l2[2][threadIdx.x] + l2[3][threadIdx.x];
    float* slot = stats + (size_t)(blockIdx.x & (NSLOT - 1)) * 128;
    atomicAdd(&slot[threadIdx.x], t1);
    atomicAdd(&slot[64 + threadIdx.x], t2);
  }
}

__global__ void k_finalize_stats(const float* __restrict__ stats,
    const float* __restrict__ bn_w, const float* __restrict__ bn_b,
    float* __restrict__ ab, int n) {
  int f = threadIdx.x;
  if (f < 64) {
    float s1 = 0.f, s2 = 0.f;
#pragma unroll 4
    for (int j = 0; j < NSLOT; ++j) {
      s1 += stats[(size_t)j * 128 + f];
      s2 += stats[(size_t)j * 128 + 64 + f];
    }
    float inv_n = 1.0f / (float)n;
    float mu = s1 * inv_n;
    float var = s2 * inv_n - mu * mu;
    float s = bn_w[f] * rsqrtf(var + 1e-5f);
    ab[f] = s;
    ab[64 + f] = bn_b[f] - mu * s;
  }
}

// ---------------------------------------------------------------- GEMM2 (fp16 in) with fused BN affine + SELU -> Y fp16 (Nx16)
__global__ __launch_bounds__(256) void k_gemm2(const unsigned short* __restrict__ A,
    const float* __restrict__ ab, const float* __restrict__ W2,
    unsigned short* __restrict__ Y, int n) {
  int row = blockIdx.x * 256 + threadIdx.x;
  if (row >= n) return;
  float4 acc0 = make_float4(0, 0, 0, 0), acc1 = acc0, acc2 = acc0, acc3 = acc0;
  const uint4* A4 = (const uint4*)(A + (size_t)row * 64);
#pragma unroll
  for (int kb = 0; kb < 8; ++kb) {
    uint4 a = A4[kb];
    unsigned int pk[4] = {a.x, a.y, a.z, a.w};
#pragma unroll
    for (int q = 0; q < 4; ++q) {
      float2 f2v = h22f2(pk[q]);
#pragma unroll
      for (int h = 0; h < 2; ++h) {
        int k = kb * 8 + 2 * q + h;
        float f = h ? f2v.y : f2v.x;
        float y = ab[k] * f + ab[64 + k];
        y = y > 0.f ? SELU_LAMBDA * y : SELU_LAMBDA * SELU_ALPHA * expm1f(y);
        const float4* Wr = (const float4*)&W2[k * 16];
        float4 w0 = Wr[0], w1 = Wr[1], w2 = Wr[2], w3 = Wr[3];
        acc0.x += y * w0.x; acc0.y += y * w0.y; acc0.z += y * w0.z; acc0.w += y * w0.w;
        acc1.x += y * w1.x; acc1.y += y * w1.y; acc1.z += y * w1.z; acc1.w += y * w1.w;
        acc2.x += y * w2.x; acc2.y += y * w2.y; acc2.z += y * w2.z; acc2.w += y * w2.w;
        acc3.x += y * w3.x; acc3.y += y * w3.y; acc3.z += y * w3.z; acc3.w += y * w3.w;
      }
    }
  }
  uint4 o;
  o.x = f2h2(acc0.x, acc0.y); o.y = f2h2(acc0.z, acc0.w);
  o.z = f2h2(acc1.x, acc1.y); o.w = f2h2(acc1.z, acc1.w);
  uint4 o2;
  o2.x = f2h2(acc2.x, acc2.y); o2.y = f2h2(acc2.z, acc2.w);
  o2.z = f2h2(acc3.x, acc3.y); o2.w = f2h2(acc3.z, acc3.w);
  uint4* op = (uint4*)(Y + (size_t)row * 16);
  op[0] = o;
  op[1] = o2;
}

// ---------------------------------------------------------------- hop at D=16 (fp16 in) + b2 + log_softmax
// one wave per node; 8 subgroups x 8 lanes; lane loads uint (2 dims, half2)
// -> one gather covers 8 edges, 1 packed add per edge. Pad with zero row n.
__global__ __launch_bounds__(256) void k_hop16(const unsigned short* __restrict__ Y,
    const float* __restrict__ b2, float* __restrict__ out,
    const int* __restrict__ offs, const int* __restrict__ csr, int n) {
  int wid = (blockIdx.x * 256 + threadIdx.x) >> 6;
  if (wid >= n) return;
  int lane = threadIdx.x & 63;
  int sub = lane >> 3, t = lane & 7;   // lane covers dims 2t, 2t+1
  int beg = offs[wid], end = offs[wid + 1];
  unsigned int accp = 0u;
  for (int eb = beg; eb < end; eb += 8) {
    int a = eb + sub;
    int idx = (a < end) ? csr[a] : n;   // row n = zero pad
    accp = hadd2(accp, *(const unsigned int*)&Y[(size_t)idx * 16 + 2 * t]);
  }
  // fp16 partials -> fp32 for the cross-subgroup reduction and softmax
  float2 pf = h22f2(accp);
  float a0 = pf.x, a1 = pf.y;
  a0 += __shfl_down(a0, 32, 64); a1 += __shfl_down(a1, 32, 64);
  a0 += __shfl_down(a0, 16, 64); a1 += __shfl_down(a1, 16, 64);
  a0 += __shfl_down(a0, 8, 64);  a1 += __shfl_down(a1, 8, 64);
  if (sub == 0) {
    float2 sf = h22f2(*(const unsigned int*)&Y[(size_t)wid * 16 + 2 * t]);
    float2 bb = *(const float2*)&b2[2 * t];
    float v0 = a0 + sf.x + bb.x;
    float v1 = a1 + sf.y + bb.y;
    float m = fmaxf(v0, v1);
#pragma unroll
    for (int d = 4; d >= 1; d >>= 1) m = fmaxf(m, __shfl_xor(m, d, 8));
    float s = expf(v0 - m) + expf(v1 - m);
#pragma unroll
    for (int d = 4; d >= 1; d >>= 1) s += __shfl_xor(s, d, 8);
    float ls = m + logf(s);
    *(float2*)&out[(size_t)wid * 16 + 2 * t] = make_float2(v0 - ls, v1 - ls);
  }
}

// ---------------------------------------------------------------- launch
extern "C" void kernel_launch(void* const* d_in, const int* in_sizes, int n_in,
                              void* d_out, int out_size, void* d_ws, size_t ws_size,
                              hipStream_t stream) {
  const float* x   = (const float*)d_in[0];
  const int* esrc  = (const int*)d_in[1];
  const int* edst  = (const int*)d_in[2];
  const float* W1  = (const float*)d_in[3];
  // d_in[4] = b1: cancels exactly under batchnorm mean subtraction
  const float* bnw = (const float*)d_in[5];
  const float* bnb = (const float*)d_in[6];
  const float* W2  = (const float*)d_in[7];
  const float* b2  = (const float*)d_in[8];
  float* out = (float*)d_out;

  const int N = in_sizes[0] / 128;  // 100000
  const int E = in_sizes[1];        // 1600000
  const int NB = (N + BNODES - 1) >> BSHIFT;  // 196 buckets

  char* p = (char*)d_ws;
  auto alloc = [&](size_t bytes) {
    char* q = p;
    p += (bytes + 255) & ~(size_t)255;
    return q;
  };
  int* cursor  = (int*)alloc(256 * sizeof(int));
  int* binned  = (int*)alloc((size_t)NB * CAP * sizeof(int));
  int* offs    = (int*)alloc((size_t)(N + 4) * sizeof(int));
  int* csr     = (int*)alloc((size_t)E * sizeof(int));
  float* stats = (float*)alloc((size_t)NSLOT * 128 * sizeof(float));
  float* ab    = (float*)alloc(128 * sizeof(float));
  unsigned short* Wfrag = (unsigned short*)alloc(1024 * 8 * sizeof(unsigned short));
  unsigned short* h1 = (unsigned short*)alloc((size_t)(N + 1) * 64 * sizeof(unsigned short));
  unsigned short* h2 = (unsigned short*)alloc((size_t)(N + 1) * 64 * sizeof(unsigned short));
  unsigned short* h3 = (unsigned short*)alloc((size_t)N * 64 * sizeof(unsigned short));
  unsigned short* Yb = (unsigned short*)alloc((size_t)(N + 1) * 16 * sizeof(unsigned short));

  // one setup kernel zeroes cursor, stats, and the three zero-pad rows
  k_zero<<<(NSLOT * 128 + 255) / 256, 256, 0, stream>>>(
      cursor, stats, h1 + (size_t)N * 64, h2 + (size_t)N * 64, Yb + (size_t)N * 16);

  // CSR build: bin -> per-bucket build (bucket scan folded into k_build)
  k_bin<<<(E + CHUNK - 1) / CHUNK, 256, 0, stream>>>(esrc, edst, cursor, binned, E);
  k_build<<<NB, 256, 0, stream>>>(binned, cursor, offs, csr, N, NB, E);

  // GEMM first (propagation commutes with the linear layer): hops run at D=64 fp16
  k_prepW<<<4, 256, 0, stream>>>(W1, Wfrag);
  k_gemm1<<<(N + 63) / 64, 256, 0, stream>>>(x, Wfrag, h1, N);

  int hopBlocks = (N * 64 + 255) / 256;  // one wave per node
  k_hop64b<<<hopBlocks, 256, 0, stream>>>(h1, h2, offs, csr, N);
  k_hop64b_stats<<<hopBlocks, 256, 0, stream>>>(h2, h3, offs, csr, stats, N);

  k_finalize_stats<<<1, 64, 0, stream>>>(stats, bnw, bnb, ab, N);

  // GEMM2 (with fused BN+SELU) before the last hop: hop runs at D=16 fp16
  k_gemm2<<<(N + 255) / 256, 256, 0, stream>>>(h3, ab, W2, Yb, N);
  k_hop16<<<hopBlocks, 256, 0, stream>>>(Yb, b2, out, offs, csr, N);
}

// Round 13
// 219.715 us; speedup vs baseline: 1.4020x; 1.0214x over previous
//
#include <hip/hip_runtime.h>
#include <hip/hip_fp16.h>
#include <math.h>

#define SELU_LAMBDA 1.0507009873554805f
#define SELU_ALPHA  1.6732632423543772f

#define BSHIFT 9
#define BNODES 512          // nodes per bucket
#define CAP    10240        // bucket capacity (mean 8192, +22 sigma)
#define CHUNK  4096         // edges per k_bin block
#define NSLOT  64           // stats atomic spreading slots

typedef _Float16 half8 __attribute__((ext_vector_type(8)));
typedef float f32x4 __attribute__((ext_vector_type(4)));

// fp16 helpers (h buffers are fp16: better mantissa than bf16, range is ample)
__device__ __forceinline__ unsigned int f2h2(float a, float b) {
  __half2 h = __floats2half2_rn(a, b);
  return *(unsigned int*)&h;
}
__device__ __forceinline__ float2 h22f2(unsigned int u) {
  __half2 h = *(__half2*)&u;
  return __half22float2(h);
}
__device__ __forceinline__ unsigned int hadd2(unsigned int a, unsigned int b) {
  __half2 x = *(__half2*)&a, y = *(__half2*)&b;
  __half2 r = __hadd2(x, y);
  return *(unsigned int*)&r;
}

// ---------------------------------------------------------------- setup: zero cursor/stats/pad rows
__global__ __launch_bounds__(256) void k_zero(int* __restrict__ cursor,
    float* __restrict__ stats, unsigned short* __restrict__ h1pad,
    unsigned short* __restrict__ h2pad, unsigned short* __restrict__ ybpad) {
  int i = blockIdx.x * 256 + threadIdx.x;
  if (i < 256) cursor[i] = 0;
  if (i < NSLOT * 128) stats[i] = 0.f;
  if (i < 64) { h1pad[i] = 0; h2pad[i] = 0; }
  if (i < 16) ybpad[i] = 0;
}

// ---------------------------------------------------------------- phase 1: bin edges by dst bucket
// packed entry: src | (dstLocal << 17)   (src < 2^17, dstLocal < 2^9)
__global__ __launch_bounds__(256) void k_bin(const int* __restrict__ src,
    const int* __restrict__ dst, int* __restrict__ cursor,
    int* __restrict__ binned, int e) {
  __shared__ int hist[256];
  __shared__ int gb[256];
  const int tid = threadIdx.x;
  hist[tid] = 0;
  __syncthreads();
  const int base = blockIdx.x * CHUNK;
  int bk[16], rk[16], pk[16];
#pragma unroll
  for (int k = 0; k < 16; ++k) {
    int i = base + k * 256 + tid;
    if (i < e) {
      int d = dst[i];
      int s = src[i];
      int b = d >> BSHIFT;
      bk[k] = b;
      pk[k] = s | ((d & (BNODES - 1)) << 17);
      rk[k] = atomicAdd(&hist[b], 1);
    } else {
      bk[k] = -1;
    }
  }
  __syncthreads();
  int h = hist[tid];
  if (h > 0) gb[tid] = atomicAdd(&cursor[tid], h);
  __syncthreads();
#pragma unroll
  for (int k = 0; k < 16; ++k) {
    if (bk[k] >= 0) binned[bk[k] * CAP + gb[bk[k]] + rk[k]] = pk[k];
  }
}

// ---------------------------------------------------------------- phase 2: per-bucket CSR build (one wg owns one bucket)
__global__ __launch_bounds__(256) void k_build(const int* __restrict__ binned,
    const int* __restrict__ cursor, int* __restrict__ offs,
    int* __restrict__ csr, int n, int nb, int etot) {
  __shared__ int sc[2][256];
  __shared__ int deg[BNODES];
  __shared__ int pre[BNODES];
  __shared__ int wsum[4];
  __shared__ int stage[CAP];
  __shared__ int s_cbase;
  const int b = blockIdx.x;
  const int tid = threadIdx.x;

  // replicated inclusive scan of the nb bucket counts
  int v0 = (tid < nb) ? cursor[tid] : 0;
  sc[0][tid] = v0;
  __syncthreads();
  int cur = 0;
  for (int d = 1; d < 256; d <<= 1) {
    int t = sc[cur][tid];
    if (tid >= d) t += sc[cur][tid - d];
    sc[cur ^ 1][tid] = t;
    cur ^= 1;
    __syncthreads();
  }
  if (tid == 0) {
    s_cbase = (b == 0) ? 0 : sc[cur][b - 1];
    if (b == 0) offs[n] = etot;
  }
  deg[tid] = 0;
  deg[tid + 256] = 0;
  __syncthreads();
  const int cbase = s_cbase;
  const int cnt = sc[cur][b] - cbase;

  const int nodeBase = b << BSHIFT;
  const int* gsrc = binned + b * CAP;

  for (int i = tid; i < cnt; i += 256) atomicAdd(&deg[gsrc[i] >> 17], 1);
  __syncthreads();

  // exclusive scan of deg[512]: 2 elements/thread
  const int lane = tid & 63, w = tid >> 6;
  int a0 = deg[2 * tid], a1 = deg[2 * tid + 1];
  int ps = a0 + a1;
  int s = ps;
#pragma unroll
  for (int d = 1; d < 64; d <<= 1) {
    int t = __shfl_up(s, d, 64);
    if (lane >= d) s += t;
  }
  if (lane == 63) wsum[w] = s;
  __syncthreads();
  if (tid == 0) {
    int acc = 0;
#pragma unroll
    for (int j = 0; j < 4; ++j) { int t = wsum[j]; wsum[j] = acc; acc += t; }
  }
  __syncthreads();
  int ex = wsum[w] + s - ps;
  pre[2 * tid] = ex;
  pre[2 * tid + 1] = ex + a0;
  // reset deg for use as cursor
  deg[tid] = 0;
  deg[tid + 256] = 0;
  __syncthreads();

  const int nNodes = min(BNODES, n - nodeBase);
  for (int i = tid; i < nNodes; i += 256) offs[nodeBase + i] = cbase + pre[i];

  for (int i = tid; i < cnt; i += 256) {
    int v = gsrc[i];
    int dl = v >> 17;
    int p = pre[dl] + atomicAdd(&deg[dl], 1);
    stage[p] = v & 0x1FFFF;
  }
  __syncthreads();
  for (int i = tid; i < cnt; i += 256) csr[cbase + i] = stage[i];
}

// ---------------------------------------------------------------- W1 fragment prep for MFMA gemm1
// Wfrag[(ntile*4+kb)*64+lane] = 8 fp16: element j = W1[kb*32+(lane>>4)*8+j][ntile*16+(lane&15)]
__global__ __launch_bounds__(256) void k_prepW(const float* __restrict__ W1,
    unsigned short* __restrict__ Wfrag) {
  int e = threadIdx.x + blockIdx.x * 256;   // 1024 entries, grid 4x256
  if (e >= 1024) return;
  int lane = e & 63;
  int kb = (e >> 6) & 3;
  int ntile = e >> 8;
  int k0 = kb * 32 + (lane >> 4) * 8;
  int col = ntile * 16 + (lane & 15);
  unsigned short tmp[8];
#pragma unroll
  for (int j = 0; j < 8; ++j) {
    __half h = __float2half_rn(W1[(size_t)(k0 + j) * 64 + col]);
    tmp[j] = *(unsigned short*)&h;
  }
  uint4* o = (uint4*)&Wfrag[(size_t)e * 8];
  *o = *(uint4*)tmp;
}

// ---------------------------------------------------------------- GEMM1 via MFMA: H1 = x @ W1 (fp16 out)
__global__ __launch_bounds__(256) void k_gemm1(
    const float* __restrict__ A, const unsigned short* __restrict__ Wfrag,
    unsigned short* __restrict__ H, int n) {
  const int lane = threadIdx.x & 63;
  const int wv = threadIdx.x >> 6;
  const int r0 = blockIdx.x * 64 + wv * 16;

  const int brow = r0 + (lane & 15);           // B-frag source row of x
  const int browc = brow < n ? brow : n - 1;
  const float* xrow = A + (size_t)browc * 128 + (lane >> 4) * 8;

  f32x4 acc[4] = {};
#pragma unroll
  for (int kb = 0; kb < 4; ++kb) {
    float4 p = *(const float4*)(xrow + kb * 32);
    float4 q = *(const float4*)(xrow + kb * 32 + 4);
    half8 xf;
    xf[0] = (_Float16)p.x; xf[1] = (_Float16)p.y;
    xf[2] = (_Float16)p.z; xf[3] = (_Float16)p.w;
    xf[4] = (_Float16)q.x; xf[5] = (_Float16)q.y;
    xf[6] = (_Float16)q.z; xf[7] = (_Float16)q.w;
#pragma unroll
    for (int nt = 0; nt < 4; ++nt) {
      half8 wf = *(const half8*)&Wfrag[(size_t)((nt * 4 + kb) * 64 + lane) * 8];
      acc[nt] = __builtin_amdgcn_mfma_f32_16x16x32_f16(wf, xf, acc[nt], 0, 0, 0);
    }
  }
  const int orow = r0 + (lane & 15);
  if (orow < n) {
#pragma unroll
    for (int nt = 0; nt < 4; ++nt) {
      int col = nt * 16 + (lane >> 4) * 4;
      uint2 o;
      o.x = f2h2(acc[nt][0], acc[nt][1]);
      o.y = f2h2(acc[nt][2], acc[nt][3]);
      *(uint2*)&H[(size_t)orow * 64 + col] = o;
    }
  }
}

// ---------------------------------------------------------------- hop at D=64 (fp16 in/out)
// one wave per node; 4 sub-groups of 16 lanes; lane loads 4 dims (8B).
// All 32 edge indices preloaded (pad = zero row n) -> 8 gathers in flight,
// one csr->gather dependency round. Tail only for deg > 32 (P ~ 1e-4).
__device__ __forceinline__ void hop64_gather32(const unsigned short* __restrict__ hin,
    const int* __restrict__ csr, int beg, int end, int sub, int t, int npad,
    unsigned int& a01, unsigned int& a23) {
  a01 = 0u; a23 = 0u;
  int idx[8];
#pragma unroll
  for (int k = 0; k < 8; ++k) {
    int a = beg + k * 4 + sub;
    idx[k] = (a < end) ? csr[a] : npad;   // pad -> zero row, no masking needed
  }
  uint2 v[8];
#pragma unroll
  for (int k = 0; k < 8; ++k)
    v[k] = *(const uint2*)&hin[(size_t)idx[k] * 64 + 4 * t];
#pragma unroll
  for (int k = 0; k < 8; ++k) {
    a01 = hadd2(a01, v[k].x);
    a23 = hadd2(a23, v[k].y);
  }
  // rare tail: deg > 32
  for (int eb = beg + 32; eb < end; eb += 16) {
    int jx[4];
#pragma unroll
    for (int k = 0; k < 4; ++k) {
      int a = eb + k * 4 + sub;
      jx[k] = (a < end) ? csr[a] : npad;
    }
    uint2 w[4];
#pragma unroll
    for (int k = 0; k < 4; ++k)
      w[k] = *(const uint2*)&hin[(size_t)jx[k] * 64 + 4 * t];
#pragma unroll
    for (int k = 0; k < 4; ++k) {
      a01 = hadd2(a01, w[k].x);
      a23 = hadd2(a23, w[k].y);
    }
  }
}

__global__ __launch_bounds__(256) void k_hop64b(const unsigned short* __restrict__ hin,
    unsigned short* __restrict__ hout, const int* __restrict__ offs,
    const int* __restrict__ csr, int n) {
  int wid = (blockIdx.x * 256 + threadIdx.x) >> 6;
  if (wid >= n) return;
  int lane = threadIdx.x & 63;
  int sub = lane >> 4, t = lane & 15;
  int beg = offs[wid], end = offs[wid + 1];
  unsigned int a01, a23;
  hop64_gather32(hin, csr, beg, end, sub, t, n, a01, a23);
  a01 = hadd2(a01, (unsigned int)__shfl_down((int)a01, 32, 64));
  a23 = hadd2(a23, (unsigned int)__shfl_down((int)a23, 32, 64));
  a01 = hadd2(a01, (unsigned int)__shfl_down((int)a01, 16, 64));
  a23 = hadd2(a23, (unsigned int)__shfl_down((int)a23, 16, 64));
  if (sub == 0) {
    uint2 sv = *(const uint2*)&hin[(size_t)wid * 64 + 4 * t];
    uint2 o;
    o.x = hadd2(a01, sv.x);
    o.y = hadd2(a23, sv.y);
    *(uint2*)&hout[(size_t)wid * 64 + 4 * t] = o;
  }
}

// hop2: fp16 in/out, fused per-column (sum, sumsq) batch stats (fp32 epilogue)
__global__ __launch_bounds__(256) void k_hop64b_stats(const unsigned short* __restrict__ hin,
    unsigned short* __restrict__ hout, const int* __restrict__ offs,
    const int* __restrict__ csr, float* __restrict__ stats, int n) {
  int wid = (blockIdx.x * 256 + threadIdx.x) >> 6;
  int lane = threadIdx.x & 63;
  int sub = lane >> 4, t = lane & 15;
  float f0 = 0.f, f1 = 0.f, f2 = 0.f, f3 = 0.f;
  if (wid < n) {
    int beg = offs[wid], end = offs[wid + 1];
    unsigned int a01, a23;
    hop64_gather32(hin, csr, beg, end, sub, t, n, a01, a23);
    a01 = hadd2(a01, (unsigned int)__shfl_down((int)a01, 32, 64));
    a23 = hadd2(a23, (unsigned int)__shfl_down((int)a23, 32, 64));
    a01 = hadd2(a01, (unsigned int)__shfl_down((int)a01, 16, 64));
    a23 = hadd2(a23, (unsigned int)__shfl_down((int)a23, 16, 64));
    if (sub == 0) {
      uint2 sv = *(const uint2*)&hin[(size_t)wid * 64 + 4 * t];
      uint2 o;
      o.x = hadd2(a01, sv.x);
      o.y = hadd2(a23, sv.y);
      *(uint2*)&hout[(size_t)wid * 64 + 4 * t] = o;
      float2 p01 = h22f2(o.x), p23 = h22f2(o.y);
      f0 = p01.x; f1 = p01.y; f2 = p23.x; f3 = p23.y;
    }
  }
  __shared__ float l1[4][64];
  __shared__ float l2[4][64];
  const int w = threadIdx.x >> 6;
  if (sub == 0) {
    *(float4*)&l1[w][4 * t] = make_float4(f0, f1, f2, f3);
    *(float4*)&l2[w][4 * t] = make_float4(f0 * f0, f1 * f1, f2 * f2, f3 * f3);
  }
  __syncthreads();
  if (threadIdx.x < 64) {
    float t1 = l1[0][threadIdx.x] + l1[1][threadIdx.x] + l1[2][threadIdx.x] + l1[3][threadIdx.x];
    float t2 = l2[0][threadIdx.x] + l2[1][threadIdx.x] + l2[2][threadIdx.x] + l2[3][threadIdx.x];
    float* slot = stats + (size_t)(blockIdx.x & (NSLOT - 1)) * 128;
    atomicAdd(&slot[threadIdx.x], t1);
    atomicAdd(&slot[64 + threadIdx.x], t2);
  }
}

__global__ void k_finalize_stats(const float* __restrict__ stats,
    const float* __restrict__ bn_w, const float* __restrict__ bn_b,
    float* __restrict__ ab, int n) {
  int f = threadIdx.x;
  if (f < 64) {
    float s1 = 0.f, s2 = 0.f;
#pragma unroll 4
    for (int j = 0; j < NSLOT; ++j) {
      s1 += stats[(size_t)j * 128 + f];
      s2 += stats[(size_t)j * 128 + 64 + f];
    }
    float inv_n = 1.0f / (float)n;
    float mu = s1 * inv_n;
    float var = s2 * inv_n - mu * mu;
    float s = bn_w[f] * rsqrtf(var + 1e-5f);
    ab[f] = s;
    ab[64 + f] = bn_b[f] - mu * s;
  }
}

// ---------------------------------------------------------------- GEMM2 (fp16 in) with fused BN affine + SELU -> Y fp16 (Nx16)
__global__ __launch_bounds__(256) void k_gemm2(const unsigned short* __restrict__ A,
    const float* __restrict__ ab, const float* __restrict__ W2,
    unsigned short* __restrict__ Y, int n) {
  int row = blockIdx.x * 256 + threadIdx.x;
  if (row >= n) return;
  float4 acc0 = make_float4(0, 0, 0, 0), acc1 = acc0, acc2 = acc0, acc3 = acc0;
  const uint4* A4 = (const uint4*)(A + (size_t)row * 64);
#pragma unroll
  for (int kb = 0; kb < 8; ++kb) {
    uint4 a = A4[kb];
    unsigned int pk[4] = {a.x, a.y, a.z, a.w};
#pragma unroll
    for (int q = 0; q < 4; ++q) {
      float2 f2v = h22f2(pk[q]);
#pragma unroll
      for (int h = 0; h < 2; ++h) {
        int k = kb * 8 + 2 * q + h;
        float f = h ? f2v.y : f2v.x;
        float y = ab[k] * f + ab[64 + k];
        y = y > 0.f ? SELU_LAMBDA * y : SELU_LAMBDA * SELU_ALPHA * expm1f(y);
        const float4* Wr = (const float4*)&W2[k * 16];
        float4 w0 = Wr[0], w1 = Wr[1], w2 = Wr[2], w3 = Wr[3];
        acc0.x += y * w0.x; acc0.y += y * w0.y; acc0.z += y * w0.z; acc0.w += y * w0.w;
        acc1.x += y * w1.x; acc1.y += y * w1.y; acc1.z += y * w1.z; acc1.w += y * w1.w;
        acc2.x += y * w2.x; acc2.y += y * w2.y; acc2.z += y * w2.z; acc2.w += y * w2.w;
        acc3.x += y * w3.x; acc3.y += y * w3.y; acc3.z += y * w3.z; acc3.w += y * w3.w;
      }
    }
  }
  uint4 o;
  o.x = f2h2(acc0.x, acc0.y); o.y = f2h2(acc0.z, acc0.w);
  o.z = f2h2(acc1.x, acc1.y); o.w = f2h2(acc1.z, acc1.w);
  uint4 o2;
  o2.x = f2h2(acc2.x, acc2.y); o2.y = f2h2(acc2.z, acc2.w);
  o2.z = f2h2(acc3.x, acc3.y); o2.w = f2h2(acc3.z, acc3.w);
  uint4* op = (uint4*)(Y + (size_t)row * 16);
  op[0] = o;
  op[1] = o2;
}

// ---------------------------------------------------------------- hop at D=16 (fp16 in) + b2 + log_softmax
// one wave per node; 8 subgroups x 8 lanes; lane loads uint (2 dims, half2)
// 24 edge indices preloaded (3 gathers in flight); tail for deg > 24 (P~2%).
__global__ __launch_bounds__(256) void k_hop16(const unsigned short* __restrict__ Y,
    const float* __restrict__ b2, float* __restrict__ out,
    const int* __restrict__ offs, const int* __restrict__ csr, int n) {
  int wid = (blockIdx.x * 256 + threadIdx.x) >> 6;
  if (wid >= n) return;
  int lane = threadIdx.x & 63;
  int sub = lane >> 3, t = lane & 7;   // lane covers dims 2t, 2t+1
  int beg = offs[wid], end = offs[wid + 1];
  int i0, i1, i2;
  {
    int a0i = beg + sub, a1i = beg + 8 + sub, a2i = beg + 16 + sub;
    i0 = (a0i < end) ? csr[a0i] : n;
    i1 = (a1i < end) ? csr[a1i] : n;
    i2 = (a2i < end) ? csr[a2i] : n;
  }
  unsigned int v0 = *(const unsigned int*)&Y[(size_t)i0 * 16 + 2 * t];
  unsigned int v1 = *(const unsigned int*)&Y[(size_t)i1 * 16 + 2 * t];
  unsigned int v2 = *(const unsigned int*)&Y[(size_t)i2 * 16 + 2 * t];
  unsigned int accp = hadd2(hadd2(v0, v1), v2);
  for (int eb = beg + 24; eb < end; eb += 8) {
    int a = eb + sub;
    int idx = (a < end) ? csr[a] : n;
    accp = hadd2(accp, *(const unsigned int*)&Y[(size_t)idx * 16 + 2 * t]);
  }
  // fp16 partials -> fp32 for the cross-subgroup reduction and softmax
  float2 pf = h22f2(accp);
  float a0 = pf.x, a1 = pf.y;
  a0 += __shfl_down(a0, 32, 64); a1 += __shfl_down(a1, 32, 64);
  a0 += __shfl_down(a0, 16, 64); a1 += __shfl_down(a1, 16, 64);
  a0 += __shfl_down(a0, 8, 64);  a1 += __shfl_down(a1, 8, 64);
  if (sub == 0) {
    float2 sf = h22f2(*(const unsigned int*)&Y[(size_t)wid * 16 + 2 * t]);
    float2 bb = *(const float2*)&b2[2 * t];
    float v0f = a0 + sf.x + bb.x;
    float v1f = a1 + sf.y + bb.y;
    float m = fmaxf(v0f, v1f);
#pragma unroll
    for (int d = 4; d >= 1; d >>= 1) m = fmaxf(m, __shfl_xor(m, d, 8));
    float s = expf(v0f - m) + expf(v1f - m);
#pragma unroll
    for (int d = 4; d >= 1; d >>= 1) s += __shfl_xor(s, d, 8);
    float ls = m + logf(s);
    *(float2*)&out[(size_t)wid * 16 + 2 * t] = make_float2(v0f - ls, v1f - ls);
  }
}

// ---------------------------------------------------------------- launch
extern "C" void kernel_launch(void* const* d_in, const int* in_sizes, int n_in,
                              void* d_out, int out_size, void* d_ws, size_t ws_size,
                              hipStream_t stream) {
  const float* x   = (const float*)d_in[0];
  const int* esrc  = (const int*)d_in[1];
  const int* edst  = (const int*)d_in[2];
  const float* W1  = (const float*)d_in[3];
  // d_in[4] = b1: cancels exactly under batchnorm mean subtraction
  const float* bnw = (const float*)d_in[5];
  const float* bnb = (const float*)d_in[6];
  const float* W2  = (const float*)d_in[7];
  const float* b2  = (const float*)d_in[8];
  float* out = (float*)d_out;

  const int N = in_sizes[0] / 128;  // 100000
  const int E = in_sizes[1];        // 1600000
  const int NB = (N + BNODES - 1) >> BSHIFT;  // 196 buckets

  char* p = (char*)d_ws;
  auto alloc = [&](size_t bytes) {
    char* q = p;
    p += (bytes + 255) & ~(size_t)255;
    return q;
  };
  int* cursor  = (int*)alloc(256 * sizeof(int));
  int* binned  = (int*)alloc((size_t)NB * CAP * sizeof(int));
  int* offs    = (int*)alloc((size_t)(N + 4) * sizeof(int));
  int* csr     = (int*)alloc((size_t)E * sizeof(int));
  float* stats = (float*)alloc((size_t)NSLOT * 128 * sizeof(float));
  float* ab    = (float*)alloc(128 * sizeof(float));
  unsigned short* Wfrag = (unsigned short*)alloc(1024 * 8 * sizeof(unsigned short));
  unsigned short* h1 = (unsigned short*)alloc((size_t)(N + 1) * 64 * sizeof(unsigned short));
  unsigned short* h2 = (unsigned short*)alloc((size_t)(N + 1) * 64 * sizeof(unsigned short));
  unsigned short* h3 = (unsigned short*)alloc((size_t)N * 64 * sizeof(unsigned short));
  unsigned short* Yb = (unsigned short*)alloc((size_t)(N + 1) * 16 * sizeof(unsigned short));

  // one setup kernel zeroes cursor, stats, and the three zero-pad rows
  k_zero<<<(NSLOT * 128 + 255) / 256, 256, 0, stream>>>(
      cursor, stats, h1 + (size_t)N * 64, h2 + (size_t)N * 64, Yb + (size_t)N * 16);

  // CSR build: bin -> per-bucket build (bucket scan folded into k_build)
  k_bin<<<(E + CHUNK - 1) / CHUNK, 256, 0, stream>>>(esrc, edst, cursor, binned, E);
  k_build<<<NB, 256, 0, stream>>>(binned, cursor, offs, csr, N, NB, E);

  // GEMM first (propagation commutes with the linear layer): hops run at D=64 fp16
  k_prepW<<<4, 256, 0, stream>>>(W1, Wfrag);
  k_gemm1<<<(N + 63) / 64, 256, 0, stream>>>(x, Wfrag, h1, N);

  int hopBlocks = (N * 64 + 255) / 256;  // one wave per node
  k_hop64b<<<hopBlocks, 256, 0, stream>>>(h1, h2, offs, csr, N);
  k_hop64b_stats<<<hopBlocks, 256, 0, stream>>>(h2, h3, offs, csr, stats, N);

  k_finalize_stats<<<1, 64, 0, stream>>>(stats, bnw, bnb, ab, N);

  // GEMM2 (with fused BN+SELU) before the last hop: hop runs at D=16 fp16
  k_gemm2<<<(N + 255) / 256, 256, 0, stream>>>(h3, ab, W2, Yb, N);
  k_hop16<<<hopBlocks, 256, 0, stream>>>(Yb, b2, out, offs, csr, N);
}